// Round 7
// baseline (243.910 us; speedup 1.0000x reference)
//
#include <hip/hip_runtime.h>

// out[r, i] = sum_{k=0..4} W[i,k] * x[r, i+k-2] + b[i], zero-padded at edges.
// B=8192 rows, C=4096 channels, K=5, fp32.
//
// R1-R4: direct-load variants, best ~76 us (shfl halo).
// R5/R6: register software pipelines FAILED (compiler sinks loads or spills).
// R7: global_load_lds staging, stage->BARRIER->compute, 1024-ch slices: 67 us.
//     Drain sits before compute -> duty-cycled in-flight, cross-block only.
// R8: 2-phase dbuf w/ __syncthreads FAILED (81 us): barrier drains vmcnt(0)
//     incl. the t+1 stages; distance-1 prefetch can't cover queued latency;
//     4 drains/block vs R7's 1. (= m218: drain-0 ~= no pipeline.)
// R9 (this): T3/T4 proper. FULL-ROW tiles (4096 ch = 16KB) -> NO halo at all.
//     3-buffer LDS (48KB, 3 blocks/CU), prefetch distance 2, raw s_barrier +
//     counted asm vmcnt (never 0 in loop). Per-wave VMEM sequence is uniform:
//     tile t wait = vmcnt(8) steady (4 stores(t-1) + 4 stages(t+1) younger),
//     vmcnt(4) at t=0 and t=NT-1. Each wave holds ~8KB in flight CONTINUOUSLY
//     -> per-CU sustained outstanding ~96KB (vs duty-cycled before).
//     TLP traded for ILP: 12 waves/CU (Occupancy ~37% expected - intentional).
// Hooks: LDS=49152, VGPR ~130-170 (if 32 -> W not held, theory dead),
//     WRITE=131072KB. If >=65 us clean -> DRAM r/w-mix wall -> roofline.

#define B_ROWS 8192
#define C_CH   4096
#define NT     8          // rows (tiles) per block
#define NBUF   3          // prefetch distance 2

typedef unsigned int u32;

__global__ __launch_bounds__(256, 3) void grouped_linear_kernel(
    const float* __restrict__ x, const float* __restrict__ W,
    const float* __restrict__ bias, float* __restrict__ out)
{
    __shared__ __align__(16) float lds[NBUF][C_CH];   // 3 x 16KB = 48KB

    const int tid  = threadIdx.x;
    const int wave = tid >> 6;
    const int lane = tid & 63;
    const int r0   = blockIdx.x * NT;

    // --- loop-invariant: each thread owns chunks q*256+tid (q=0..3) ---
    // W rows for 4 channels = 20 contiguous floats = 5 float4 per chunk.
    float4 w0[4], w1[4], w2[4], w3[4], w4[4], bv[4];
    #pragma unroll
    for (int q = 0; q < 4; ++q) {
        const int chunk = q * 256 + tid;
        const float4* W4p = (const float4*)(W + (size_t)chunk * 20);
        w0[q] = W4p[0];  // W[c][0..3]
        w1[q] = W4p[1];  // W[c][4], W[c+1][0..2]
        w2[q] = W4p[2];  // W[c+1][3..4], W[c+2][0..1]
        w3[q] = W4p[3];  // W[c+2][2..4], W[c+3][0]
        w4[q] = W4p[4];  // W[c+3][1..4]
        bv[q] = ((const float4*)bias)[chunk];
    }

    // staging: wave w owns quarter-row [w*1024 .. w*1024+1023] floats,
    // moved as 4 x 1KB global_load_lds (dest = wave-uniform base + lane*16B).
    const float* xw = x + (size_t)r0 * C_CH + wave * 1024 + lane * 4;

#define STAGE(t_) {                                                            \
    const float* g_ = xw + (size_t)(t_) * C_CH;                                \
    float* d_ = &lds[(t_) % NBUF][wave * 1024];                                \
    _Pragma("unroll")                                                          \
    for (int i_ = 0; i_ < 4; ++i_)                                             \
        __builtin_amdgcn_global_load_lds(                                      \
            (const __attribute__((address_space(1))) u32*)(g_ + i_ * 256),     \
            (__attribute__((address_space(3))) u32*)(d_ + i_ * 256),           \
            16, 0, 0);                                                         \
  }

    STAGE(0);
    STAGE(1);

    #pragma unroll
    for (int t = 0; t < NT; ++t) {
        // wait for tile t's 4 stages; younger ops: steady = 4 stores(t-1) +
        // 4 stages(t+1) = 8; at t==0 only stages(1)=4; at t==NT-1 only
        // stores(NT-2)=4. NEVER vmcnt(0) in the loop.
        if (t == 0 || t == NT - 1) {
            asm volatile("s_waitcnt vmcnt(4)" ::: "memory");
        } else {
            asm volatile("s_waitcnt vmcnt(8)" ::: "memory");
        }
        __builtin_amdgcn_s_barrier();   // raw: no compiler-forced drain

        const float* row = lds[t % NBUF];
        float4* orow = (float4*)(out + (size_t)(r0 + t) * C_CH);

        #pragma unroll
        for (int q = 0; q < 4; ++q) {
            const int chunk = q * 256 + tid;
            const int f = chunk * 4;
            // full row in LDS -> halo is just neighboring floats; only the
            // global channel edges (chunk 0 / 1023) need zero-select, with
            // clamped (valid) addresses.
            const float4 pm = *(const float4*)(row + (chunk > 0    ? f - 4 : 0));
            const float4 pc = *(const float4*)(row + f);
            const float4 pp = *(const float4*)(row + (chunk < 1023 ? f + 4 : f));
            const bool lo = (chunk == 0), hi = (chunk == 1023);

            const float win0 = lo ? 0.f : pm.z, win1 = lo ? 0.f : pm.w;
            const float win2 = pc.x, win3 = pc.y, win4 = pc.z, win5 = pc.w;
            const float win6 = hi ? 0.f : pp.x, win7 = hi ? 0.f : pp.y;

            float4 o;
            o.x = fmaf(w0[q].x, win0, fmaf(w0[q].y, win1, fmaf(w0[q].z, win2, fmaf(w0[q].w, win3, fmaf(w1[q].x, win4, bv[q].x)))));
            o.y = fmaf(w1[q].y, win1, fmaf(w1[q].z, win2, fmaf(w1[q].w, win3, fmaf(w2[q].x, win4, fmaf(w2[q].y, win5, bv[q].y)))));
            o.z = fmaf(w2[q].z, win2, fmaf(w2[q].w, win3, fmaf(w3[q].x, win4, fmaf(w3[q].y, win5, fmaf(w3[q].z, win6, bv[q].z)))));
            o.w = fmaf(w3[q].w, win3, fmaf(w4[q].x, win4, fmaf(w4[q].y, win5, fmaf(w4[q].z, win6, fmaf(w4[q].w, win7, bv[q].w)))));

            orow[chunk] = o;   // 4 store instrs/wave/tile, fire-and-forget
        }

        if (t + 2 < NT) STAGE(t + 2);   // keep distance-2 prefetch in flight
    }
}

extern "C" void kernel_launch(void* const* d_in, const int* in_sizes, int n_in,
                              void* d_out, int out_size, void* d_ws, size_t ws_size,
                              hipStream_t stream) {
    const float* x    = (const float*)d_in[0];
    const float* W    = (const float*)d_in[1];
    const float* bias = (const float*)d_in[2];
    float* out = (float*)d_out;

    dim3 grid(B_ROWS / NT);   // 1024 blocks, 4 per CU of work, 3 resident
    dim3 block(256);
    grouped_linear_kernel<<<grid, block, 0, stream>>>(x, W, bias, out);
}

// Round 8
// 233.150 us; speedup vs baseline: 1.0461x; 1.0461x over previous
//
#include <hip/hip_runtime.h>

// out[r, i] = sum_{k=0..4} W[i,k] * x[r, i+k-2] + b[i], zero-padded at edges.
// B=8192 rows, C=4096 channels, K=5, fp32.
//
// R1-R4: direct-load variants, best ~76 us (shfl halo).
// R5/R6: register software pipelines FAILED (compiler sinks loads or spills).
// R7: global_load_lds staging, ONE-SHOT block (stage -> barrier -> compute ->
//     exit), 256thr/1024ch/4rows, 8 blocks/CU + 4096-deep queue: ~67 us. BEST.
//     The working pipeline is the block dispatcher: new blocks' stages overlap
//     sibling blocks' compute. In-block scheduling attempts both lost:
// R8: dbuf + drain-per-tile: 81 us (vmcnt(0) serializes tiles).
// R9: counted-vmcnt + 48KB LDS + 1024-block grid: 99 us (killed TLP:
//     occupancy 23%, 4 blocks/CU of work, no backfill; VGPR 80).
// R10 (this): push R7's own axis - MORE, SMALLER independent one-shot blocks.
//     128 threads (2 waves) x 512-ch slice x 4 rows. 16 blocks/CU resident
//     (still full 32 waves; LDS 8.3KB x 16 = 133KB), 16 independent stage
//     phases/CU (smoother read stream, 2-wave barriers), 16384-block grid =
//     64 queued/CU (finer backfill, smaller tail). Same stage/halo/compute
//     mechanics as R7.
// Readout: kernel <80us is invisible to top-5 -> bench-160us arithmetic.
// If delta within noise -> ~4 TB/s demand is the mixed-stream wall -> roofline.

#define B_ROWS 8192
#define C_CH   4096
#define NROWS  4       // rows staged per block
#define SLICE  512     // channels per block slice
#define NCHK   (SLICE / 4)   // 128 float4 chunks per slice

typedef unsigned int u32;

__global__ __launch_bounds__(128, 8) void grouped_linear_kernel(
    const float* __restrict__ x, const float* __restrict__ W,
    const float* __restrict__ bias, float* __restrict__ out)
{
    __shared__ __align__(16) float lds_rows[NROWS][SLICE];
    __shared__ __align__(16) float lds_hL[NROWS][4];  // [2],[3] = x[row][sl-2..sl-1]
    __shared__ __align__(16) float lds_hR[NROWS][4];  // [0],[1] = x[row][sl+512..513]

    const int tid   = threadIdx.x;        // 0..127
    const int bx    = blockIdx.x;         // 0..7
    const int r0    = blockIdx.y * NROWS;
    const int chunk = bx * NCHK + tid;    // global float4 index in row
    const int c     = chunk << 2;

    // --- loop-invariant: W rows c..c+3 (20 contiguous floats) + bias ---
    const float4* W4 = (const float4*)(W + (size_t)c * 5);
    const float4 w0 = W4[0];  // W[c][0..3]
    const float4 w1 = W4[1];  // W[c][4], W[c+1][0..2]
    const float4 w2 = W4[2];  // W[c+1][3..4], W[c+2][0..1]
    const float4 w3 = W4[3];  // W[c+2][2..4], W[c+3][0]
    const float4 w4 = W4[4];  // W[c+3][1..4]
    const float4 bv = ((const float4*)bias)[chunk];

    // ---- stage NROWS x 2KB row-slices into LDS (no dest VGPRs) ----
    {
        const int wave = tid >> 6;
        const int lane = tid & 63;
        const float* gsrc0 = x + (size_t)r0 * C_CH + bx * SLICE + wave * 256 + lane * 4;
        #pragma unroll
        for (int r = 0; r < NROWS; ++r)
            __builtin_amdgcn_global_load_lds(
                (const __attribute__((address_space(1))) u32*)(gsrc0 + r * C_CH),
                (__attribute__((address_space(3))) u32*)&lds_rows[r][wave * 256],
                16, 0, 0);
    }

    // ---- slice-edge halos: 2 float2 per row, staged by threads 0..7 ----
    if (tid < 2 * NROWS) {
        const int  hr    = tid >> 1;
        const int  right = tid & 1;
        const int  gc    = bx * SLICE + (right ? SLICE : -2);  // first channel of float2
        float2 v = make_float2(0.f, 0.f);
        if (gc >= 0 && gc + 1 < C_CH)
            v = *(const float2*)(x + (size_t)(r0 + hr) * C_CH + gc);
        float* dst = right ? &lds_hR[hr][0] : &lds_hL[hr][2];
        *(float2*)dst = v;
    }

    __syncthreads();   // drains vmcnt(0)+lgkmcnt(0): tile fully resident

    float4* obase = (float4*)(out + (size_t)r0 * C_CH) + chunk;
    const int f = tid * 4;   // local float index of this thread's window center

    #pragma unroll
    for (int r = 0; r < NROWS; ++r) {
        const float* rowp = lds_rows[r];
        // Edge lanes redirect the read ADDRESS to the halo slot; payload lanes
        // read the canonical stride-16B pattern.
        const float4 pm = (tid > 0)
            ? *(const float4*)(rowp + f - 4)
            : *(const float4*)lds_hL[r];        // .z,.w = win0,win1
        const float4 pc = *(const float4*)(rowp + f);
        const float4 pp = (tid < NCHK - 1)
            ? *(const float4*)(rowp + f + 4)
            : *(const float4*)lds_hR[r];        // .x,.y = win6,win7

        // win[m] = x[r, c - 2 + m], m = 0..7
        const float win0 = pm.z, win1 = pm.w;
        const float win2 = pc.x, win3 = pc.y, win4 = pc.z, win5 = pc.w;
        const float win6 = pp.x, win7 = pp.y;

        float4 o;
        o.x = fmaf(w0.x, win0, fmaf(w0.y, win1, fmaf(w0.z, win2, fmaf(w0.w, win3, fmaf(w1.x, win4, bv.x)))));
        o.y = fmaf(w1.y, win1, fmaf(w1.z, win2, fmaf(w1.w, win3, fmaf(w2.x, win4, fmaf(w2.y, win5, bv.y)))));
        o.z = fmaf(w2.z, win2, fmaf(w2.w, win3, fmaf(w3.x, win4, fmaf(w3.y, win5, fmaf(w3.z, win6, bv.z)))));
        o.w = fmaf(w3.w, win3, fmaf(w4.x, win4, fmaf(w4.y, win5, fmaf(w4.z, win6, fmaf(w4.w, win7, bv.w)))));

        obase[r * (C_CH / 4)] = o;
    }
}

extern "C" void kernel_launch(void* const* d_in, const int* in_sizes, int n_in,
                              void* d_out, int out_size, void* d_ws, size_t ws_size,
                              hipStream_t stream) {
    const float* x    = (const float*)d_in[0];
    const float* W    = (const float*)d_in[1];
    const float* bias = (const float*)d_in[2];
    float* out = (float*)d_out;

    dim3 grid(C_CH / SLICE, B_ROWS / NROWS);   // (8, 2048) = 16384 blocks
    dim3 block(128);
    grouped_linear_kernel<<<grid, block, 0, stream>>>(x, W, bias, out);
}